// Round 7
// baseline (102.241 us; speedup 1.0000x reference)
//
#include <hip/hip_runtime.h>
#include <hip/hip_bf16.h>

// ---- problem constants ----
#define BATCH   4096
#define FEAT    1024
#define NTREES  10
#define NNODES  255
#define NLEAF   256
#define NCLS    1000
#define KTOT    (NTREES*NLEAF) // 2560 = GEMM2 K

typedef __attribute__((ext_vector_type(8))) short  bf16x8;
typedef __attribute__((ext_vector_type(4))) float  f32x4;

// workspace layout (bytes)
#define OFF_XB 0u
#define OFF_WT 8388608u
#define OFF_PT 13631488u
#define OFF_RT 18874368u

#define WAITVM(N) asm volatile("s_waitcnt vmcnt(" #N ")" ::: "memory")
#define BAR() __builtin_amdgcn_s_barrier()

__device__ __forceinline__ void load_lds16(const void* g, void* l) {
    __builtin_amdgcn_global_load_lds(
        (const __attribute__((address_space(1))) unsigned int*)g,
        (__attribute__((address_space(3))) unsigned int*)l, 16, 0, 0);
}

// Pair-row LDS layout: lds-row R (128B) holds global rows {2R, 2R+1} (64B each,
// i.e. one K=32 bf16 slice), slot-permuted by XOR with (R&7).
//   content at [R*128 + slot*16] = global row 2R+h, chunk ch, where h*4+ch = slot^(R&7)
//   read row ra chunk s: byte = (ra>>1)*128 + ((((ra&1)<<2)+s) ^ ((ra>>1)&7))*16
// 16 lanes reading consecutive ra at fixed s alias exactly 2-way (free, m136).

// ---------------- fused conversion kernel ----------------
__global__ void k_cvt_all(const float* __restrict__ x, const float* __restrict__ w,
                          const float* __restrict__ p,
                          __hip_bfloat16* __restrict__ xb,
                          __hip_bfloat16* __restrict__ wT,
                          __hip_bfloat16* __restrict__ pT) {
    __shared__ float tile[32][33];
    const int bid = blockIdx.x;
    const int tid = threadIdx.x;

    if (bid < 4096) {
        int i = bid * 256 + tid;
        float4 v = reinterpret_cast<const float4*>(x)[i];
        union { ushort4 u; __hip_bfloat16 h[4]; } o;
        o.h[0] = __float2bfloat16(v.x);
        o.h[1] = __float2bfloat16(v.y);
        o.h[2] = __float2bfloat16(v.z);
        o.h[3] = __float2bfloat16(v.w);
        reinterpret_cast<ushort4*>(xb)[i] = o.u;
    } else if (bid < 6656) {
        int idx = bid - 4096;              // 2560: t(10) x fb(32) x nb(8)
        int t  = idx >> 8;
        int fb = ((idx >> 3) & 31) * 32;
        int nb = (idx & 7) * 32;
        int tx = tid & 31, ty = tid >> 5;
#pragma unroll
        for (int j = 0; j < 4; ++j) {
            int f = fb + ty + j * 8;
            int n = nb + tx;
            float v = (n < NNODES) ? w[((size_t)t * FEAT + f) * NNODES + n] : 0.f;
            tile[ty + j * 8][tx] = v;
        }
        __syncthreads();
#pragma unroll
        for (int j = 0; j < 4; ++j) {
            int n = nb + ty + j * 8;
            int f = fb + tx;
            wT[((size_t)t * NLEAF + n) * FEAT + f] = __float2bfloat16(tile[tx][ty + j * 8]);
        }
    } else {
        int idx = bid - 6656;              // 2560: kb(80) x cb(32)
        int cb = (idx & 31) * 32;
        int kb = (idx >> 5) * 32;
        int tx = tid & 31, ty = tid >> 5;
#pragma unroll
        for (int j = 0; j < 4; ++j) {
            int k = kb + ty + j * 8;
            int c = cb + tx;
            float v = (c < NCLS) ? p[(size_t)k * NCLS + c] * 0.1f : 0.f;
            tile[ty + j * 8][tx] = v;
        }
        __syncthreads();
#pragma unroll
        for (int j = 0; j < 4; ++j) {
            int c = cb + ty + j * 8;
            int k = kb + tx;
            pT[(size_t)c * KTOT + k] = __float2bfloat16(tile[tx][ty + j * 8]);
        }
    }
}

// ---------------- GEMM1 + sigmoid + routing ----------------
// tile 64(M) x 256(N=one tree), 256 thr = 4 waves, wave 64x64 (wn = wid).
// K-32 phases, ring-3 x 20KB = 60KB -> 2 blocks/CU. Counted WAITVM(5),
// stage(p+2) after BAR. Pair-row XOR-8 LDS (<=2-way conflicts).
__global__ __launch_bounds__(256, 2) void k_gemm1_route(
        const __hip_bfloat16* __restrict__ xb,
        const __hip_bfloat16* __restrict__ wT,
        __hip_bfloat16* __restrict__ route) {
    __shared__ __align__(16) char smem[61440];    // 3 x (A 4KB + B 16KB); Ds[64][132] f32 = 33.8KB

    int wg = blockIdx.x;                          // 640 blocks
    int sw = (wg & 7) * 80 + (wg >> 3);           // 8 XCD x 80
    const int bm = sw & 63;
    const int tr = sw >> 6;

    const int tid = threadIdx.x;
    const int lane = tid & 63, wid = tid >> 6;    // 4 waves
    const int wn = wid;

    f32x4 acc[4][4] = {};

    const __hip_bfloat16* Ag = xb + (size_t)(bm * 64) * FEAT;
    const __hip_bfloat16* Bg = wT + (size_t)tr * NLEAF * FEAT;

    const int NT = FEAT / 32;                     // 32 phases

    // stage unit p (20KB): 5 loads/thread (1 A + 4 B), pre-swizzled source, linear dest
    auto stage = [&](int p) {
        const int k0 = p * 32;
        char* base = smem + (p % 3) * 20480;
        {   // A: 64 rows -> 32 lds-rows, 256 chunks, 1/thread
            int d = tid, R = d >> 3, x = (d & 7) ^ (R & 7);
            int grow = 2 * R + ((x >> 2) & 1), ch = x & 3;
            load_lds16(Ag + (size_t)grow * FEAT + k0 + ch * 8, base + d * 16);
        }
#pragma unroll
        for (int q = 0; q < 4; ++q) {             // B: 256 rows -> 128 lds-rows, 1024 chunks
            int d = q * 256 + tid, R = d >> 3, x = (d & 7) ^ (R & 7);
            int grow = 2 * R + ((x >> 2) & 1), ch = x & 3;
            load_lds16(Bg + (size_t)grow * FEAT + k0 + ch * 8, base + 4096 + d * 16);
        }
    };

    stage(0); stage(1);                           // 10 loads in flight

    for (int p = 0; p < NT; ++p) {
        if (p < NT - 1) { WAITVM(5); }            // unit p landed, p+1 in flight
        else            { WAITVM(0); }
        BAR();                                    // all waves' unit-p loads visible
        if (p + 2 < NT) stage(p + 2);             // slot (p+2)%3 = (p-1)%3: readers done

        const char* As = smem + (p % 3) * 20480;
        const char* Bs = As + 4096;
        const int s0 = lane >> 4;
        bf16x8 a[4], b[4];
#pragma unroll
        for (int f = 0; f < 4; ++f) {
            int ra = f * 16 + (lane & 15);
            int Rr = ra >> 1;
            a[f] = *(const bf16x8*)(As + Rr * 128 + (((((ra & 1) << 2) + s0) ^ (Rr & 7)) << 4));
            int rb = wn * 64 + f * 16 + (lane & 15);
            int Rb = rb >> 1;
            b[f] = *(const bf16x8*)(Bs + Rb * 128 + (((((rb & 1) << 2) + s0) ^ (Rb & 7)) << 4));
        }
        __builtin_amdgcn_s_setprio(1);
#pragma unroll
        for (int mf = 0; mf < 4; ++mf)
#pragma unroll
            for (int nf = 0; nf < 4; ++nf)
                acc[mf][nf] = __builtin_amdgcn_mfma_f32_16x16x32_bf16(
                    a[mf], b[nf], acc[mf][nf], 0, 0, 0);
        __builtin_amdgcn_s_setprio(0);
    }

    __syncthreads();                              // ring dead; reuse as Ds

    // ---- epilogue: sigmoid nodes 0..126 -> Ds; level-7 from regs; write 2 leaves packed
    float* Ds = (float*)smem;                     // [64][132] fp32
    if (wn < 2) {
#pragma unroll
        for (int mf = 0; mf < 4; ++mf)
#pragma unroll
            for (int nf = 0; nf < 4; ++nf) {
                int col = wn * 64 + nf * 16 + (lane & 15);
                if (col < 127) {
#pragma unroll
                    for (int r = 0; r < 4; ++r) {
                        int row = mf * 16 + (lane >> 4) * 4 + r;
                        float z = acc[mf][nf][r];
                        Ds[row * 132 + col] = 1.f / (1.f + __expf(-z));
                    }
                }
            }
    }
    __syncthreads();
    if (wn >= 1) {
#pragma unroll
        for (int mf = 0; mf < 4; ++mf)
#pragma unroll
            for (int nf = 0; nf < 4; ++nf) {
                int col = wn * 64 + nf * 16 + (lane & 15);
                if (col >= 127 && col <= 254) {
                    int pnode = col - 127;
#pragma unroll
                    for (int r = 0; r < 4; ++r) {
                        int row = mf * 16 + (lane >> 4) * 4 + r;
                        float prefix = 1.f;
#pragma unroll
                        for (int l = 0; l < 7; ++l) {
                            int node = (1 << l) - 1 + (pnode >> (7 - l));
                            float v = Ds[row * 132 + node];
                            prefix *= (((pnode >> (6 - l)) & 1) == 0) ? v : (1.f - v);
                        }
                        float wv = 1.f / (1.f + __expf(-acc[mf][nf][r]));
                        union { unsigned int u; __hip_bfloat16 h[2]; } pk;
                        pk.h[0] = __float2bfloat16(prefix * wv);
                        pk.h[1] = __float2bfloat16(prefix * (1.f - wv));
                        int bb = bm * 64 + row;
                        *(unsigned int*)(route + (size_t)bb * KTOT + tr * NLEAF + 2 * pnode) = pk.u;
                    }
                }
            }
    }
}

// ---------------- GEMM2 + clip ----------------
// tile 128x128, grid 256 (1/CU), 512 thr = 8 waves: in-block K-split-2,
// each half 2x2 waves of 64x64, BK=32, ring-4 per half (128KB), depth-3 counted
// vmcnt. Pair-row XOR-8 LDS. Loop: {WAITVM; BAR; stage(t+3); ds_read; MFMA}
__global__ __launch_bounds__(512, 2) void k_gemm2(
        const __hip_bfloat16* __restrict__ route,
        const __hip_bfloat16* __restrict__ pT,
        float* __restrict__ out) {
    __shared__ __align__(16) char smem[131072];

    int wg = blockIdx.x;                          // 256 blocks
    int sw = (wg & 7) * 32 + (wg >> 3);           // 8 XCD x 32
    const int bm = sw >> 3;
    const int bn = sw & 7;

    const int tid = threadIdx.x;
    const int lane = tid & 63, wid = tid >> 6;
    const int h  = wid >> 2;                      // K half
    const int w2 = wid & 3;
    const int wm = w2 >> 1, wn = w2 & 1;
    const int htid = w2 * 64 + lane;              // 0..255 within half

    f32x4 acc[4][4] = {};

    const __hip_bfloat16* Ag = route + (size_t)(bm * 128) * KTOT + h * 1280;
    const __hip_bfloat16* Bg = pT + (size_t)(bn * 128) * KTOT + h * 1280;
    char* bufH = smem + h * 65536;

    const int NT = 1280 / 32;                     // 40

    // unit 16KB (A 8KB + B 8KB): 4 loads/thread (2 A + 2 B)
    auto stage = [&](int t) {
        const int k0 = t * 32;
        char* base = bufH + (t & 3) * 16384;
#pragma unroll
        for (int q = 0; q < 2; ++q) {
            int d = q * 256 + htid, R = d >> 3, x = (d & 7) ^ (R & 7);
            int grow = 2 * R + ((x >> 2) & 1), ch = x & 3;   // 0..127
            load_lds16(Ag + (size_t)grow * KTOT + k0 + ch * 8, base + d * 16);
            load_lds16(Bg + (size_t)grow * KTOT + k0 + ch * 8, base + 8192 + d * 16);
        }
    };

    stage(0); stage(1); stage(2);                 // 12 loads in flight

    for (int t = 0; t < NT; ++t) {
        if (t < NT - 2)       { WAITVM(8); }      // tile t landed, t+1..t+2 in flight
        else if (t == NT - 2) { WAITVM(4); }
        else                  { WAITVM(0); }
        BAR();
        if (t + 3 < NT) stage(t + 3);             // slot (t+3)&3 = (t-1)&3: readers done

        const char* As = bufH + (t & 3) * 16384;
        const char* Bs = As + 8192;
        const int s0 = lane >> 4;
        bf16x8 a[4], b[4];
#pragma unroll
        for (int f = 0; f < 4; ++f) {
            int ra = wm * 64 + f * 16 + (lane & 15);
            int Rr = ra >> 1;
            a[f] = *(const bf16x8*)(As + Rr * 128 + (((((ra & 1) << 2) + s0) ^ (Rr & 7)) << 4));
            int rb = wn * 64 + f * 16 + (lane & 15);
            int Rb = rb >> 1;
            b[f] = *(const bf16x8*)(Bs + Rb * 128 + (((((rb & 1) << 2) + s0) ^ (Rb & 7)) << 4));
        }
        __builtin_amdgcn_s_setprio(1);
#pragma unroll
        for (int mf = 0; mf < 4; ++mf)
#pragma unroll
            for (int nf = 0; nf < 4; ++nf)
                acc[mf][nf] = __builtin_amdgcn_mfma_f32_16x16x32_bf16(
                    a[mf], b[nf], acc[mf][nf], 0, 0, 0);
        __builtin_amdgcn_s_setprio(0);
    }

    // ---- cross-half reduce via LDS, then clip + store ----
    __syncthreads();
    float* R = (float*)smem;                      // 4 quads x [64][65] f32
    if (h == 1) {
#pragma unroll
        for (int mf = 0; mf < 4; ++mf)
#pragma unroll
            for (int nf = 0; nf < 4; ++nf)
#pragma unroll
                for (int r = 0; r < 4; ++r) {
                    int row = mf * 16 + (lane >> 4) * 4 + r;
                    int col = nf * 16 + (lane & 15);
                    R[w2 * 4160 + row * 65 + col] = acc[mf][nf][r];
                }
    }
    __syncthreads();
    if (h == 0) {
#pragma unroll
        for (int mf = 0; mf < 4; ++mf)
#pragma unroll
            for (int nf = 0; nf < 4; ++nf)
#pragma unroll
                for (int r = 0; r < 4; ++r) {
                    int row = mf * 16 + (lane >> 4) * 4 + r;
                    int col = nf * 16 + (lane & 15);
                    float v = acc[mf][nf][r] + R[w2 * 4160 + row * 65 + col];
                    v = fminf(fmaxf(v, 0.f), 1.f);
                    int grow = bm * 128 + wm * 64 + row;
                    int gcol = bn * 128 + wn * 64 + col;
                    if (gcol < NCLS)
                        out[(size_t)grow * NCLS + gcol] = v;
                }
    }
}

extern "C" void kernel_launch(void* const* d_in, const int* in_sizes, int n_in,
                              void* d_out, int out_size, void* d_ws, size_t ws_size,
                              hipStream_t stream) {
    const float* x = (const float*)d_in[0];
    const float* w = (const float*)d_in[1];
    const float* p = (const float*)d_in[2];
    float* out = (float*)d_out;
    char* ws = (char*)d_ws;

    __hip_bfloat16* xb    = (__hip_bfloat16*)(ws + OFF_XB);
    __hip_bfloat16* wT    = (__hip_bfloat16*)(ws + OFF_WT);
    __hip_bfloat16* pT    = (__hip_bfloat16*)(ws + OFF_PT);
    __hip_bfloat16* route = (__hip_bfloat16*)(ws + OFF_RT);

    k_cvt_all<<<9216, 256, 0, stream>>>(x, w, p, xb, wT, pT);
    k_gemm1_route<<<640, 256, 0, stream>>>(xb, wT, route);
    k_gemm2<<<256, 512, 0, stream>>>(route, pT, out);
}

// Round 8
// 101.391 us; speedup vs baseline: 1.0084x; 1.0084x over previous
//
#include <hip/hip_runtime.h>
#include <hip/hip_bf16.h>

// ---- problem constants ----
#define BATCH   4096
#define FEAT    1024
#define NTREES  10
#define NNODES  255
#define NLEAF   256
#define NCLS    1000
#define KTOT    (NTREES*NLEAF) // 2560 = GEMM2 K

typedef __attribute__((ext_vector_type(8))) short  bf16x8;
typedef __attribute__((ext_vector_type(4))) float  f32x4;

// workspace layout (bytes)
#define OFF_XB 0u
#define OFF_WT 8388608u
#define OFF_PT 13631488u
#define OFF_RT 18874368u

#define WAITVM(N) asm volatile("s_waitcnt vmcnt(" #N ")" ::: "memory")
#define WAITLGKM() asm volatile("s_waitcnt lgkmcnt(0)" ::: "memory")
#define BAR() __builtin_amdgcn_s_barrier()

__device__ __forceinline__ void load_lds16(const void* g, void* l) {
    __builtin_amdgcn_global_load_lds(
        (const __attribute__((address_space(1))) unsigned int*)g,
        (__attribute__((address_space(3))) unsigned int*)l, 16, 0, 0);
}

// LDS tile layout (BK=64): row r = 128B; 16B chunk s of row r stored at
// byte r*128 + ((s ^ (r&7)) << 4). Staged linearly: dest chunk d (=R*8+c)
// holds global chunk x = c ^ (R&7) of global row R (pre-swizzled source).
// 16 consecutive rows at fixed s -> 2-way bank aliasing only (free, m136).

// ---------------- fused conversion kernel ----------------
__global__ void k_cvt_all(const float* __restrict__ x, const float* __restrict__ w,
                          const float* __restrict__ p,
                          __hip_bfloat16* __restrict__ xb,
                          __hip_bfloat16* __restrict__ wT,
                          __hip_bfloat16* __restrict__ pT) {
    __shared__ float tile[32][33];
    const int bid = blockIdx.x;
    const int tid = threadIdx.x;

    if (bid < 4096) {
        int i = bid * 256 + tid;
        float4 v = reinterpret_cast<const float4*>(x)[i];
        union { ushort4 u; __hip_bfloat16 h[4]; } o;
        o.h[0] = __float2bfloat16(v.x);
        o.h[1] = __float2bfloat16(v.y);
        o.h[2] = __float2bfloat16(v.z);
        o.h[3] = __float2bfloat16(v.w);
        reinterpret_cast<ushort4*>(xb)[i] = o.u;
    } else if (bid < 6656) {
        int idx = bid - 4096;              // 2560: t(10) x fb(32) x nb(8)
        int t  = idx >> 8;
        int fb = ((idx >> 3) & 31) * 32;
        int nb = (idx & 7) * 32;
        int tx = tid & 31, ty = tid >> 5;
#pragma unroll
        for (int j = 0; j < 4; ++j) {
            int f = fb + ty + j * 8;
            int n = nb + tx;
            float v = (n < NNODES) ? w[((size_t)t * FEAT + f) * NNODES + n] : 0.f;
            tile[ty + j * 8][tx] = v;
        }
        __syncthreads();
#pragma unroll
        for (int j = 0; j < 4; ++j) {
            int n = nb + ty + j * 8;
            int f = fb + tx;
            wT[((size_t)t * NLEAF + n) * FEAT + f] = __float2bfloat16(tile[tx][ty + j * 8]);
        }
    } else {
        int idx = bid - 6656;              // 2560: kb(80) x cb(32)
        int cb = (idx & 31) * 32;
        int kb = (idx >> 5) * 32;
        int tx = tid & 31, ty = tid >> 5;
#pragma unroll
        for (int j = 0; j < 4; ++j) {
            int k = kb + ty + j * 8;
            int c = cb + tx;
            float v = (c < NCLS) ? p[(size_t)k * NCLS + c] * 0.1f : 0.f;
            tile[ty + j * 8][tx] = v;
        }
        __syncthreads();
#pragma unroll
        for (int j = 0; j < 4; ++j) {
            int c = cb + ty + j * 8;
            int k = kb + tx;
            pT[(size_t)c * KTOT + k] = __float2bfloat16(tile[tx][ty + j * 8]);
        }
    }
}

// ---------------- GEMM1 + sigmoid + routing ----------------
// tile 64(M) x 256(N=one tree), BK=64, 512 thr = 8 waves (2M x 4N, wave 32x64).
// m201-style phases: per K-tile 2 phases of {6 ds_reads || stage-part ->
// BAR -> lgkm0 -> setprio + 8 MFMA -> BAR}; ring-3 x 40KB; vmcnt counted (5).
__global__ __launch_bounds__(512, 2) void k_gemm1_route(
        const __hip_bfloat16* __restrict__ xb,
        const __hip_bfloat16* __restrict__ wT,
        __hip_bfloat16* __restrict__ route) {
    __shared__ __align__(16) char smem[122880];   // 3 x (A 8KB + B 32KB); Ds[64][132] f32 reuses slot0

    int wg = blockIdx.x;                          // 640 blocks
    int sw = (wg & 7) * 80 + (wg >> 3);           // 8 XCD x 80
    const int bm = sw & 63;
    const int tr = sw >> 6;

    const int tid = threadIdx.x;
    const int lane = tid & 63, wid = tid >> 6;
    const int wm = wid >> 2, wn = wid & 3;        // 2M x 4N, wave 32x64

    f32x4 acc[2][4] = {};

    const __hip_bfloat16* Ag = xb + (size_t)(bm * 64) * FEAT;
    const __hip_bfloat16* Bg = wT + (size_t)tr * NLEAF * FEAT;

    const int NT = FEAT / 64;                     // 16

    // stage split: p1 = A(1 load) + B q0,q1 ; p2 = B q2,q3   (5 loads/thread/tile)
    auto stage_p1 = [&](int t) {
        const int k0 = t * 64;
        char* base = smem + (t % 3) * 40960;
        {   int d = tid, R = d >> 3, x = (d & 7) ^ (R & 7);   // A: 64 rows
            load_lds16(Ag + (size_t)R * FEAT + k0 + x * 8, base + d * 16); }
#pragma unroll
        for (int q = 0; q < 2; ++q) {
            int d = q * 512 + tid, R = d >> 3, x = (d & 7) ^ (R & 7);  // B rows 0..127
            load_lds16(Bg + (size_t)R * FEAT + k0 + x * 8, base + 8192 + d * 16);
        }
    };
    auto stage_p2 = [&](int t) {
        const int k0 = t * 64;
        char* base = smem + (t % 3) * 40960;
#pragma unroll
        for (int q = 2; q < 4; ++q) {
            int d = q * 512 + tid, R = d >> 3, x = (d & 7) ^ (R & 7);  // B rows 128..255
            load_lds16(Bg + (size_t)R * FEAT + k0 + x * 8, base + 8192 + d * 16);
        }
    };

    stage_p1(0); stage_p2(0);
    stage_p1(1); stage_p2(1);                     // 10 loads in flight
    WAITVM(5);                                    // tile 0 landed, tile 1 flying
    BAR();

    for (int t = 0; t < NT; ++t) {
        const char* As = smem + (t % 3) * 40960;
        const char* Bs = As + 8192;
        const bool pf = (t + 2 < NT);

#pragma unroll
        for (int ks = 0; ks < 2; ++ks) {
            const int s = ks * 4 + (lane >> 4);
            bf16x8 a[2], b[4];
#pragma unroll
            for (int mf = 0; mf < 2; ++mf) {
                int r = wm * 32 + mf * 16 + (lane & 15);
                a[mf] = *(const bf16x8*)(As + r * 128 + ((s ^ (r & 7)) << 4));
            }
#pragma unroll
            for (int nf = 0; nf < 4; ++nf) {
                int r = wn * 64 + nf * 16 + (lane & 15);
                b[nf] = *(const bf16x8*)(Bs + r * 128 + ((s ^ (r & 7)) << 4));
            }
            if (pf) { if (ks == 0) stage_p1(t + 2); else stage_p2(t + 2); }
            BAR();
            WAITLGKM();
            __builtin_amdgcn_s_setprio(1);
#pragma unroll
            for (int mf = 0; mf < 2; ++mf)
#pragma unroll
                for (int nf = 0; nf < 4; ++nf)
                    acc[mf][nf] = __builtin_amdgcn_mfma_f32_16x16x32_bf16(
                        a[mf], b[nf], acc[mf][nf], 0, 0, 0);
            __builtin_amdgcn_s_setprio(0);
            if (ks == 1) {
                if (pf)               { WAITVM(5); }   // tile t+1 landed, t+2 flying
                else if (t + 1 < NT)  { WAITVM(0); }   // tail: drain last tile
            }
            BAR();
        }
    }

    __syncthreads();                              // ring dead; reuse as Ds

    // ---- epilogue: sigmoid nodes 0..126 -> Ds; level-7 from regs; 2 leaves packed
    float* Ds = (float*)smem;                     // [64][132] fp32
    if (wn < 2) {
#pragma unroll
        for (int mf = 0; mf < 2; ++mf)
#pragma unroll
            for (int nf = 0; nf < 4; ++nf) {
                int col = wn * 64 + nf * 16 + (lane & 15);
                if (col < 127) {
#pragma unroll
                    for (int r = 0; r < 4; ++r) {
                        int row = wm * 32 + mf * 16 + (lane >> 4) * 4 + r;
                        float z = acc[mf][nf][r];
                        Ds[row * 132 + col] = 1.f / (1.f + __expf(-z));
                    }
                }
            }
    }
    __syncthreads();
    if (wn >= 1) {
#pragma unroll
        for (int mf = 0; mf < 2; ++mf)
#pragma unroll
            for (int nf = 0; nf < 4; ++nf) {
                int col = wn * 64 + nf * 16 + (lane & 15);
                if (col >= 127 && col <= 254) {
                    int pnode = col - 127;
#pragma unroll
                    for (int r = 0; r < 4; ++r) {
                        int row = wm * 32 + mf * 16 + (lane >> 4) * 4 + r;
                        float prefix = 1.f;
#pragma unroll
                        for (int l = 0; l < 7; ++l) {
                            int node = (1 << l) - 1 + (pnode >> (7 - l));
                            float v = Ds[row * 132 + node];
                            prefix *= (((pnode >> (6 - l)) & 1) == 0) ? v : (1.f - v);
                        }
                        float wv = 1.f / (1.f + __expf(-acc[mf][nf][r]));
                        union { unsigned int u; __hip_bfloat16 h[2]; } pk;
                        pk.h[0] = __float2bfloat16(prefix * wv);
                        pk.h[1] = __float2bfloat16(prefix * (1.f - wv));
                        int bb = bm * 64 + row;
                        *(unsigned int*)(route + (size_t)bb * KTOT + tr * NLEAF + 2 * pnode) = pk.u;
                    }
                }
            }
    }
}

// ---------------- GEMM2 + clip ----------------
// tile 128x128 (grid 256 = 1 round), BK=64, 512 thr = 8 waves (2M x 4N, wave 64x32).
// Same phase template: 2 phases/tile of {6 ds_reads || stage-part -> BAR ->
// lgkm0 -> setprio + 8 MFMA -> BAR}; ring-3 x 32KB; vmcnt counted (4).
__global__ __launch_bounds__(512, 2) void k_gemm2(
        const __hip_bfloat16* __restrict__ route,
        const __hip_bfloat16* __restrict__ pT,
        float* __restrict__ out) {
    __shared__ __align__(16) char smem[98304];    // 3 x (A 16KB + B 16KB)

    int wg = blockIdx.x;                          // 256 blocks
    int sw = (wg & 7) * 32 + (wg >> 3);           // 8 XCD x 32
    const int bm = sw >> 3;                       // route-panel L2-resident per XCD
    const int bn = sw & 7;

    const int tid = threadIdx.x;
    const int lane = tid & 63, wid = tid >> 6;
    const int wm = wid >> 2, wn = wid & 3;        // 2M x 4N, wave 64x32

    f32x4 acc[4][2] = {};

    const __hip_bfloat16* Ag = route + (size_t)(bm * 128) * KTOT;
    const __hip_bfloat16* Bg = pT + (size_t)(bn * 128) * KTOT;

    const int NT = KTOT / 64;                     // 40

    // stage split: p1 = A q0,q1 ; p2 = B q0,q1  (4 loads/thread/tile)
    auto stage_p1 = [&](int t) {
        const int k0 = t * 64;
        char* base = smem + (t % 3) * 32768;
#pragma unroll
        for (int q = 0; q < 2; ++q) {
            int d = q * 512 + tid, R = d >> 3, x = (d & 7) ^ (R & 7);  // 0..127
            load_lds16(Ag + (size_t)R * KTOT + k0 + x * 8, base + d * 16);
        }
    };
    auto stage_p2 = [&](int t) {
        const int k0 = t * 64;
        char* base = smem + (t % 3) * 32768;
#pragma unroll
        for (int q = 0; q < 2; ++q) {
            int d = q * 512 + tid, R = d >> 3, x = (d & 7) ^ (R & 7);
            load_lds16(Bg + (size_t)R * KTOT + k0 + x * 8, base + 16384 + d * 16);
        }
    };

    stage_p1(0); stage_p2(0);
    stage_p1(1); stage_p2(1);                     // 8 loads in flight
    WAITVM(4);
    BAR();

    for (int t = 0; t < NT; ++t) {
        const char* As = smem + (t % 3) * 32768;
        const char* Bs = As + 16384;
        const bool pf = (t + 2 < NT);

#pragma unroll
        for (int ks = 0; ks < 2; ++ks) {
            const int s = ks * 4 + (lane >> 4);
            bf16x8 a[4], b[2];
#pragma unroll
            for (int mf = 0; mf < 4; ++mf) {
                int r = wm * 64 + mf * 16 + (lane & 15);
                a[mf] = *(const bf16x8*)(As + r * 128 + ((s ^ (r & 7)) << 4));
            }
#pragma unroll
            for (int nf = 0; nf < 2; ++nf) {
                int r = wn * 32 + nf * 16 + (lane & 15);
                b[nf] = *(const bf16x8*)(Bs + r * 128 + ((s ^ (r & 7)) << 4));
            }
            if (pf) { if (ks == 0) stage_p1(t + 2); else stage_p2(t + 2); }
            BAR();
            WAITLGKM();
            __builtin_amdgcn_s_setprio(1);
#pragma unroll
            for (int mf = 0; mf < 4; ++mf)
#pragma unroll
                for (int nf = 0; nf < 2; ++nf)
                    acc[mf][nf] = __builtin_amdgcn_mfma_f32_16x16x32_bf16(
                        a[mf], b[nf], acc[mf][nf], 0, 0, 0);
            __builtin_amdgcn_s_setprio(0);
            if (ks == 1) {
                if (pf)              { WAITVM(4); }
                else if (t + 1 < NT) { WAITVM(0); }
            }
            BAR();
        }
    }

    // ---- clip + masked store (output 1000 wide) ----
#pragma unroll
    for (int mf = 0; mf < 4; ++mf)
#pragma unroll
        for (int nf = 0; nf < 2; ++nf)
#pragma unroll
            for (int r = 0; r < 4; ++r) {
                int row = bm * 128 + wm * 64 + mf * 16 + (lane >> 4) * 4 + r;
                int col = bn * 128 + wn * 32 + nf * 16 + (lane & 15);
                if (col < NCLS) {
                    float v = acc[mf][nf][r];
                    v = fminf(fmaxf(v, 0.f), 1.f);
                    out[(size_t)row * NCLS + col] = v;
                }
            }
}

extern "C" void kernel_launch(void* const* d_in, const int* in_sizes, int n_in,
                              void* d_out, int out_size, void* d_ws, size_t ws_size,
                              hipStream_t stream) {
    const float* x = (const float*)d_in[0];
    const float* w = (const float*)d_in[1];
    const float* p = (const float*)d_in[2];
    float* out = (float*)d_out;
    char* ws = (char*)d_ws;

    __hip_bfloat16* xb    = (__hip_bfloat16*)(ws + OFF_XB);
    __hip_bfloat16* wT    = (__hip_bfloat16*)(ws + OFF_WT);
    __hip_bfloat16* pT    = (__hip_bfloat16*)(ws + OFF_PT);
    __hip_bfloat16* route = (__hip_bfloat16*)(ws + OFF_RT);

    k_cvt_all<<<9216, 256, 0, stream>>>(x, w, p, xb, wT, pT);
    k_gemm1_route<<<640, 512, 0, stream>>>(xb, wT, route);
    k_gemm2<<<256, 512, 0, stream>>>(route, pT, out);
}